// Round 6
// baseline (32825.735 us; speedup 1.0000x reference)
//
#include <hip/hip_runtime.h>
#include <hip/hip_fp16.h>
#include <stdint.h>

#define TIME_STEPS 4096
#define DIM        2048
#define NWG        256
#define NTH        128
#define NWAVE      512   // (NWG*NTH)/64, 4 rows per wave
#define RPW        4

typedef uint32_t u32x4 __attribute__((ext_vector_type(4)));
typedef _Float16 h2f16 __attribute__((ext_vector_type(2)));

// actbuf entry: u32 = (tag16 << 16) | fp16bits(act); slot t%NSLOT holds gen t
// (tag = t+1 <= 4097, fits 16 bits). All-valid check: min over dwords >= tag<<16.
// Polls use `nt` (non-temporal): read the MALL (coherence point) directly each
// round instead of spinning on a stale XCD-L2 copy waiting for invalidation.
// d_ws: [0, NSLOT*DIM*4) ring | [+, NWAVE*4) progress[wave] = last consumed gen

__device__ __forceinline__ uint32_t umin32(uint32_t a, uint32_t b) { return a < b ? a : b; }

__device__ __forceinline__ float dot2f(uint32_t packed, h2f16 w, float acc) {
#if __has_builtin(__builtin_amdgcn_fdot2)
  return __builtin_amdgcn_fdot2(__builtin_bit_cast(h2f16, packed), w, acc, false);
#else
  h2f16 a = __builtin_bit_cast(h2f16, packed);
  acc = fmaf((float)a.x, (float)w.x, acc);
  return fmaf((float)a.y, (float)w.y, acc);
#endif
}

template<int NSLOT>
__global__ __launch_bounds__(NTH, 1) void ctrnn_kernel(
    const float* __restrict__ x,        // [TIME, DIM]
    const float* __restrict__ W,        // [DIM, DIM]
    const float* __restrict__ bias,     // [DIM]
    const float* __restrict__ initial,  // [DIM]
    float* __restrict__ out,            // [TIME, DIM]
    uint32_t* __restrict__ actbuf,
    uint32_t* __restrict__ progress)
{
  const int lane = threadIdx.x & 63;
  const int wid  = (blockIdx.x << 1) | (threadIdx.x >> 6);  // 0..511
  const int s    = lane >> 2;        // 16 col-slices of 128
  const int rr   = lane & 3;         // sub-offset within each 64B line
  const int row0 = wid * RPW;
  // This thread's 32 cols: {s*128 + rr*4 + k*16 + 0..3, k=0..7}
  const int cb   = s * 128 + rr * 4;

  // W packed fp16x2: 4 rows x this thread's 32 cols = 64 VGPRs.
  h2f16 w2[4][16];
  #pragma unroll
  for (int m = 0; m < 4; ++m) {
    const float* wr = W + (size_t)(row0 + m) * DIM + cb;
    #pragma unroll
    for (int k = 0; k < 8; ++k) {
      w2[m][2*k]   = h2f16{(_Float16)wr[k*16 + 0], (_Float16)wr[k*16 + 1]};
      w2[m][2*k+1] = h2f16{(_Float16)wr[k*16 + 2], (_Float16)wr[k*16 + 3]};
    }
  }

  // State: lanes 0..3 own rows row0..row0+3.  x pipeline is 2 deep:
  // xv = x[t], xw = x[t+1]; x[t+2] issued after each poll success.
  float v = 0.f, bj = 0.f, xv = 0.f, xw = 0.f;
  if (lane < RPW) {
    const int j = row0 + lane;
    v  = initial[j];
    bj = bias[j];
    xv = x[j];
    xw = x[DIM + j];
    out[j] = v;
    const float a0 = 1.0f / (1.0f + __expf(-(v + bj)));
    __half h = __float2half_rn(a0);
    uint16_t hb; __builtin_memcpy(&hb, &h, 2);
    __hip_atomic_store(&actbuf[j], (1u << 16) | hb,
                       __ATOMIC_RELAXED, __HIP_MEMORY_SCOPE_AGENT);
  }

  uint32_t prog_seen = 0;

  for (int t = 0; t < TIME_STEPS - 1; ++t) {
    const uint32_t needtag = (uint32_t)(t + 1);
    const uint32_t thresh  = needtag << 16;
    const uint32_t* src = actbuf + (size_t)(t & (NSLOT - 1)) * DIM + cb;

    // ---- wave-synchronized poll: 8 dwordx4 nt (L2-bypassing, MALL-fresh),
    //      every 64B line read exactly once per wave per round ----
    u32x4 q[8];
    for (;;) {
      asm volatile(
        "global_load_dwordx4 %0, %8, off sc1 nt\n\t"
        "global_load_dwordx4 %1, %8, off offset:64 sc1 nt\n\t"
        "global_load_dwordx4 %2, %8, off offset:128 sc1 nt\n\t"
        "global_load_dwordx4 %3, %8, off offset:192 sc1 nt\n\t"
        "global_load_dwordx4 %4, %8, off offset:256 sc1 nt\n\t"
        "global_load_dwordx4 %5, %8, off offset:320 sc1 nt\n\t"
        "global_load_dwordx4 %6, %8, off offset:384 sc1 nt\n\t"
        "global_load_dwordx4 %7, %8, off offset:448 sc1 nt\n\t"
        "s_waitcnt vmcnt(0)"
        : "=&v"(q[0]), "=&v"(q[1]), "=&v"(q[2]), "=&v"(q[3]),
          "=&v"(q[4]), "=&v"(q[5]), "=&v"(q[6]), "=&v"(q[7])
        : "v"(src)
        : "memory");
      __builtin_amdgcn_sched_barrier(0);

      uint32_t mn = 0xFFFFFFFFu;
      #pragma unroll
      for (int k = 0; k < 8; ++k)
        mn = umin32(mn, umin32(umin32(q[k][0], q[k][1]),
                               umin32(q[k][2], q[k][3])));
      if (__all((int)(mn >= thresh))) break;
    }

    // x[t+2] prefetch issued here: ~1 full step of slack before consumption,
    // and the next poll's vmcnt(0) only fires after that slack.
    float xn = 0.f;
    if (lane < RPW && t + 2 < TIME_STEPS) xn = x[(size_t)(t + 2) * DIM + row0 + lane];

    // Announce consumption (producers gate ring reuse on this).
    if (lane == 0)
      __hip_atomic_store(&progress[wid], needtag,
                         __ATOMIC_RELAXED, __HIP_MEMORY_SCOPE_AGENT);

    // ---- dot: 4 rows x 32 cols per thread; 16 perm + 64 fdot2 ----
    float a0 = 0.f, a1 = 0.f, a2 = 0.f, a3 = 0.f;
    #pragma unroll
    for (int k = 0; k < 8; ++k) {
      const uint32_t lo = __builtin_amdgcn_perm(q[k][1], q[k][0], 0x05040100u);
      const uint32_t hi = __builtin_amdgcn_perm(q[k][3], q[k][2], 0x05040100u);
      a0 = dot2f(lo, w2[0][2*k], a0); a0 = dot2f(hi, w2[0][2*k+1], a0);
      a1 = dot2f(lo, w2[1][2*k], a1); a1 = dot2f(hi, w2[1][2*k+1], a1);
      a2 = dot2f(lo, w2[2][2*k], a2); a2 = dot2f(hi, w2[2][2*k+1], a2);
      a3 = dot2f(lo, w2[3][2*k], a3); a3 = dot2f(hi, w2[3][2*k+1], a3);
    }

    // ---- merge-reduce: lane l ends with row (l&3) total ----
    const float t0 = a0 + __shfl_xor(a0, 1, 64);
    const float t1 = a1 + __shfl_xor(a1, 1, 64);
    const float t2 = a2 + __shfl_xor(a2, 1, 64);
    const float t3 = a3 + __shfl_xor(a3, 1, 64);
    const float m01 = (lane & 1) ? t1 : t0;
    const float m23 = (lane & 1) ? t3 : t2;
    const float u01 = m01 + __shfl_xor(m01, 2, 64);
    const float u23 = m23 + __shfl_xor(m23, 2, 64);
    float p = (lane & 2) ? u23 : u01;
    p += __shfl_xor(p, 4, 64);
    p += __shfl_xor(p, 8, 64);
    p += __shfl_xor(p, 16, 64);
    p += __shfl_xor(p, 32, 64);

    // ---- WAR gate: publishing gen t+1 over slot (t+1)%NSLOT needs all waves
    //      to have consumed gen t+1-NSLOT. Fires ~every NSLOT-1 steps. ----
    if (t >= NSLOT - 1) {
      const uint32_t need = (uint32_t)(t + 2 - NSLOT);
      if (need > prog_seen) {
        for (;;) {
          uint32_t mn = 0xFFFFFFFFu;
          #pragma unroll
          for (int i = 0; i < 8; ++i)
            mn = umin32(mn, __hip_atomic_load(&progress[lane + 64*i],
                              __ATOMIC_RELAXED, __HIP_MEMORY_SCOPE_AGENT));
          uint32_t qq;
          qq = (uint32_t)__shfl_xor((int)mn, 1, 64);  mn = umin32(mn, qq);
          qq = (uint32_t)__shfl_xor((int)mn, 2, 64);  mn = umin32(mn, qq);
          qq = (uint32_t)__shfl_xor((int)mn, 4, 64);  mn = umin32(mn, qq);
          qq = (uint32_t)__shfl_xor((int)mn, 8, 64);  mn = umin32(mn, qq);
          qq = (uint32_t)__shfl_xor((int)mn, 16, 64); mn = umin32(mn, qq);
          qq = (uint32_t)__shfl_xor((int)mn, 32, 64); mn = umin32(mn, qq);
          if (mn >= need) { prog_seen = mn; break; }
        }
      }
    }

    // ---- state update + out + publish (lanes 0..3) ----
    if (lane < RPW) {
      v  = 0.9f * v + 0.1f * (p + xv);
      xv = xw;
      xw = xn;
      out[(size_t)(t + 1) * DIM + row0 + lane] = v;
      const float a = 1.0f / (1.0f + __expf(-(v + bj)));
      __half h = __float2half_rn(a);
      uint16_t hb; __builtin_memcpy(&hb, &h, 2);
      const uint32_t e = ((uint32_t)(t + 2) << 16) | hb;
      __hip_atomic_store(&actbuf[(size_t)((t + 1) & (NSLOT - 1)) * DIM + row0 + lane], e,
                         __ATOMIC_RELAXED, __HIP_MEMORY_SCOPE_AGENT);
    }
  }
}

extern "C" void kernel_launch(void* const* d_in, const int* in_sizes, int n_in,
                              void* d_out, int out_size, void* d_ws, size_t ws_size,
                              hipStream_t stream) {
  const float* x       = (const float*)d_in[0];
  const float* W       = (const float*)d_in[1];
  const float* bias    = (const float*)d_in[2];
  const float* initial = (const float*)d_in[3];
  float* out           = (float*)d_out;

  uint32_t* actbuf = (uint32_t*)d_ws;

  const size_t need32 = (size_t)32 * DIM * 4 + NWAVE * 4;
  void* kfun;
  size_t actbytes;
  if (ws_size >= need32) { kfun = (void*)ctrnn_kernel<32>; actbytes = (size_t)32 * DIM * 4; }
  else                   { kfun = (void*)ctrnn_kernel<8>;  actbytes = (size_t)8  * DIM * 4; }

  uint32_t* progress = (uint32_t*)((char*)d_ws + actbytes);

  // Tags are generation counters — clear every call (graph-capture safe).
  hipMemsetAsync(d_ws, 0, actbytes + NWAVE * 4, stream);

  void* args[] = { (void*)&x, (void*)&W, (void*)&bias, (void*)&initial,
                   (void*)&out, (void*)&actbuf, (void*)&progress };
  hipLaunchCooperativeKernel(kfun, dim3(NWG), dim3(NTH), args, 0, stream);
}

// Round 7
// 12358.668 us; speedup vs baseline: 2.6561x; 2.6561x over previous
//
#include <hip/hip_runtime.h>
#include <hip/hip_fp16.h>
#include <stdint.h>

#define TIME_STEPS 4096
#define DIM        2048
#define NWG        256
#define NTH        128
#define NWAVE      512   // (NWG*NTH)/64, 4 rows per wave
#define RPW        4

typedef uint32_t u32x4 __attribute__((ext_vector_type(4)));
typedef _Float16 h2f16 __attribute__((ext_vector_type(2)));

// actbuf entry: u32 = (tag16 << 16) | fp16bits(act); slot t%NSLOT holds gen t
// (tag = t+1 <= 4097). All-valid check: min over dwords >= tag<<16.
// NCOPY replicas of the ring: consumers poll copy (bid & (NCOPY-1)) — aligned
// with the XCD round-robin dispatch heuristic so each copy has ~1 L2 sharer;
// producers write all copies (parallel invalidations, 1 sharer each).
// d_ws: [0, NCOPY*NSLOT*DIM*4) rings | [+, NWAVE*4) progress[wave]

__device__ __forceinline__ uint32_t umin32(uint32_t a, uint32_t b) { return a < b ? a : b; }

__device__ __forceinline__ float dot2f(uint32_t packed, h2f16 w, float acc) {
#if __has_builtin(__builtin_amdgcn_fdot2)
  return __builtin_amdgcn_fdot2(__builtin_bit_cast(h2f16, packed), w, acc, false);
#else
  h2f16 a = __builtin_bit_cast(h2f16, packed);
  acc = fmaf((float)a.x, (float)w.x, acc);
  return fmaf((float)a.y, (float)w.y, acc);
#endif
}

template<int NSLOT, int NCOPY>
__global__ __launch_bounds__(NTH, 1) void ctrnn_kernel(
    const float* __restrict__ x,        // [TIME, DIM]
    const float* __restrict__ W,        // [DIM, DIM]
    const float* __restrict__ bias,     // [DIM]
    const float* __restrict__ initial,  // [DIM]
    float* __restrict__ out,            // [TIME, DIM]
    uint32_t* __restrict__ actbuf,
    uint32_t* __restrict__ progress)
{
  const int lane = threadIdx.x & 63;
  const int wid  = (blockIdx.x << 1) | (threadIdx.x >> 6);  // 0..511
  const int s    = lane >> 2;        // 16 col-slices of 128
  const int rr   = lane & 3;         // sub-offset within each 64B line
  const int row0 = wid * RPW;
  const int cb   = s * 128 + rr * 4; // cols {cb + k*16 + 0..3, k=0..7}

  // This block's poll replica (XCD-aligned under bid%NXCD round-robin).
  uint32_t* mybuf = actbuf + (size_t)(blockIdx.x & (NCOPY - 1)) * NSLOT * DIM;

  // W packed fp16x2: 4 rows x this thread's 32 cols = 64 VGPRs.
  h2f16 w2[4][16];
  #pragma unroll
  for (int m = 0; m < 4; ++m) {
    const float* wr = W + (size_t)(row0 + m) * DIM + cb;
    #pragma unroll
    for (int k = 0; k < 8; ++k) {
      w2[m][2*k]   = h2f16{(_Float16)wr[k*16 + 0], (_Float16)wr[k*16 + 1]};
      w2[m][2*k+1] = h2f16{(_Float16)wr[k*16 + 2], (_Float16)wr[k*16 + 3]};
    }
  }

  // State: lanes 0..3 own rows row0..row0+3.  x pipeline 2 deep.
  float v = 0.f, bj = 0.f, xv = 0.f, xw = 0.f;
  if (lane < RPW) {
    const int j = row0 + lane;
    v  = initial[j];
    bj = bias[j];
    xv = x[j];
    xw = x[DIM + j];
    out[j] = v;
    const float a0 = 1.0f / (1.0f + __expf(-(v + bj)));
    __half h = __float2half_rn(a0);
    uint16_t hb; __builtin_memcpy(&hb, &h, 2);
    const uint32_t e = (1u << 16) | hb;
    #pragma unroll
    for (int c = 0; c < NCOPY; ++c)
      __hip_atomic_store(&actbuf[(size_t)c * NSLOT * DIM + j], e,
                         __ATOMIC_RELAXED, __HIP_MEMORY_SCOPE_AGENT);
  }

  uint32_t prog_seen = 0;

  for (int t = 0; t < TIME_STEPS - 1; ++t) {
    const uint32_t needtag = (uint32_t)(t + 1);
    const uint32_t thresh  = needtag << 16;
    const uint32_t* src = mybuf + (size_t)(t & (NSLOT - 1)) * DIM + cb;

    // ---- wave-synchronized poll: 8 dwordx4 sc1; spins served by local L2,
    //      fresh data arrives via single-sharer invalidation of this copy ----
    u32x4 q[8];
    for (;;) {
      asm volatile(
        "global_load_dwordx4 %0, %8, off sc1\n\t"
        "global_load_dwordx4 %1, %8, off offset:64 sc1\n\t"
        "global_load_dwordx4 %2, %8, off offset:128 sc1\n\t"
        "global_load_dwordx4 %3, %8, off offset:192 sc1\n\t"
        "global_load_dwordx4 %4, %8, off offset:256 sc1\n\t"
        "global_load_dwordx4 %5, %8, off offset:320 sc1\n\t"
        "global_load_dwordx4 %6, %8, off offset:384 sc1\n\t"
        "global_load_dwordx4 %7, %8, off offset:448 sc1\n\t"
        "s_waitcnt vmcnt(0)"
        : "=&v"(q[0]), "=&v"(q[1]), "=&v"(q[2]), "=&v"(q[3]),
          "=&v"(q[4]), "=&v"(q[5]), "=&v"(q[6]), "=&v"(q[7])
        : "v"(src)
        : "memory");
      __builtin_amdgcn_sched_barrier(0);

      uint32_t mn = 0xFFFFFFFFu;
      #pragma unroll
      for (int k = 0; k < 8; ++k)
        mn = umin32(mn, umin32(umin32(q[k][0], q[k][1]),
                               umin32(q[k][2], q[k][3])));
      if (__all((int)(mn >= thresh))) break;
    }

    // x[t+2] prefetch: ~1 full step of slack before consumption.
    float xn = 0.f;
    if (lane < RPW && t + 2 < TIME_STEPS) xn = x[(size_t)(t + 2) * DIM + row0 + lane];

    // Announce consumption (producers gate ring reuse on this).
    if (lane == 0)
      __hip_atomic_store(&progress[wid], needtag,
                         __ATOMIC_RELAXED, __HIP_MEMORY_SCOPE_AGENT);

    // ---- dot: 4 rows x 32 cols per thread; 16 perm + 64 fdot2 ----
    float a0 = 0.f, a1 = 0.f, a2 = 0.f, a3 = 0.f;
    #pragma unroll
    for (int k = 0; k < 8; ++k) {
      const uint32_t lo = __builtin_amdgcn_perm(q[k][1], q[k][0], 0x05040100u);
      const uint32_t hi = __builtin_amdgcn_perm(q[k][3], q[k][2], 0x05040100u);
      a0 = dot2f(lo, w2[0][2*k], a0); a0 = dot2f(hi, w2[0][2*k+1], a0);
      a1 = dot2f(lo, w2[1][2*k], a1); a1 = dot2f(hi, w2[1][2*k+1], a1);
      a2 = dot2f(lo, w2[2][2*k], a2); a2 = dot2f(hi, w2[2][2*k+1], a2);
      a3 = dot2f(lo, w2[3][2*k], a3); a3 = dot2f(hi, w2[3][2*k+1], a3);
    }

    // ---- merge-reduce: lane l ends with row (l&3) total ----
    const float t0 = a0 + __shfl_xor(a0, 1, 64);
    const float t1 = a1 + __shfl_xor(a1, 1, 64);
    const float t2 = a2 + __shfl_xor(a2, 1, 64);
    const float t3 = a3 + __shfl_xor(a3, 1, 64);
    const float m01 = (lane & 1) ? t1 : t0;
    const float m23 = (lane & 1) ? t3 : t2;
    const float u01 = m01 + __shfl_xor(m01, 2, 64);
    const float u23 = m23 + __shfl_xor(m23, 2, 64);
    float p = (lane & 2) ? u23 : u01;
    p += __shfl_xor(p, 4, 64);
    p += __shfl_xor(p, 8, 64);
    p += __shfl_xor(p, 16, 64);
    p += __shfl_xor(p, 32, 64);

    // ---- WAR gate: publishing gen t+1 over slot (t+1)%NSLOT needs all waves
    //      (hence all replicas' consumers) past gen t+1-NSLOT. ----
    if (t >= NSLOT - 1) {
      const uint32_t need = (uint32_t)(t + 2 - NSLOT);
      if (need > prog_seen) {
        for (;;) {
          uint32_t mn = 0xFFFFFFFFu;
          #pragma unroll
          for (int i = 0; i < 8; ++i)
            mn = umin32(mn, __hip_atomic_load(&progress[lane + 64*i],
                              __ATOMIC_RELAXED, __HIP_MEMORY_SCOPE_AGENT));
          uint32_t qq;
          qq = (uint32_t)__shfl_xor((int)mn, 1, 64);  mn = umin32(mn, qq);
          qq = (uint32_t)__shfl_xor((int)mn, 2, 64);  mn = umin32(mn, qq);
          qq = (uint32_t)__shfl_xor((int)mn, 4, 64);  mn = umin32(mn, qq);
          qq = (uint32_t)__shfl_xor((int)mn, 8, 64);  mn = umin32(mn, qq);
          qq = (uint32_t)__shfl_xor((int)mn, 16, 64); mn = umin32(mn, qq);
          qq = (uint32_t)__shfl_xor((int)mn, 32, 64); mn = umin32(mn, qq);
          if (mn >= need) { prog_seen = mn; break; }
        }
      }
    }

    // ---- state update + out + publish to ALL replicas (lanes 0..3) ----
    if (lane < RPW) {
      v  = 0.9f * v + 0.1f * (p + xv);
      xv = xw;
      xw = xn;
      out[(size_t)(t + 1) * DIM + row0 + lane] = v;
      const float a = 1.0f / (1.0f + __expf(-(v + bj)));
      __half h = __float2half_rn(a);
      uint16_t hb; __builtin_memcpy(&hb, &h, 2);
      const uint32_t e = ((uint32_t)(t + 2) << 16) | hb;
      const size_t slotoff = (size_t)((t + 1) & (NSLOT - 1)) * DIM + row0 + lane;
      #pragma unroll
      for (int c = 0; c < NCOPY; ++c)
        __hip_atomic_store(&actbuf[(size_t)c * NSLOT * DIM + slotoff], e,
                           __ATOMIC_RELAXED, __HIP_MEMORY_SCOPE_AGENT);
    }
  }
}

extern "C" void kernel_launch(void* const* d_in, const int* in_sizes, int n_in,
                              void* d_out, int out_size, void* d_ws, size_t ws_size,
                              hipStream_t stream) {
  const float* x       = (const float*)d_in[0];
  const float* W       = (const float*)d_in[1];
  const float* bias    = (const float*)d_in[2];
  const float* initial = (const float*)d_in[3];
  float* out           = (float*)d_out;

  uint32_t* actbuf = (uint32_t*)d_ws;

  const size_t ring8 = (size_t)8 * 16 * DIM * 4;   // 8 copies x 16 slots = 1 MiB
  const size_t ring2 = (size_t)2 * 16 * DIM * 4;   // 256 KiB
  const size_t ring1 = (size_t)1 *  8 * DIM * 4;   // 64 KiB

  void* kfun;
  size_t actbytes;
  if (ws_size >= ring8 + NWAVE * 4)      { kfun = (void*)ctrnn_kernel<16, 8>; actbytes = ring8; }
  else if (ws_size >= ring2 + NWAVE * 4) { kfun = (void*)ctrnn_kernel<16, 2>; actbytes = ring2; }
  else                                   { kfun = (void*)ctrnn_kernel<8, 1>;  actbytes = ring1; }

  uint32_t* progress = (uint32_t*)((char*)d_ws + actbytes);

  // Tags are generation counters — clear every call (graph-capture safe).
  hipMemsetAsync(d_ws, 0, actbytes + NWAVE * 4, stream);

  void* args[] = { (void*)&x, (void*)&W, (void*)&bias, (void*)&initial,
                   (void*)&out, (void*)&actbuf, (void*)&progress };
  hipLaunchCooperativeKernel(kfun, dim3(NWG), dim3(NTH), args, 0, stream);
}

// Round 9
// 9270.583 us; speedup vs baseline: 3.5408x; 1.3331x over previous
//
#include <hip/hip_runtime.h>
#include <hip/hip_fp16.h>
#include <hip/hip_cooperative_groups.h>
#include <stdint.h>

#define TIME_STEPS 4096
#define DIM        2048
#define NBLK       256    // grid (co-resident: 1 block/CU)
#define NTH        512    // 8 waves per block
#define NWORK      32     // worker blocks (one XCD's worth of CUs)
#define WVB        8      // waves per worker block
#define RPW        8      // rows per wave: 256 waves x 8 = 2048
#define PITCH      132    // words per 128-entry slice; 132 mod 32 = 4 -> 2-way (free)

typedef uint32_t u32x4 __attribute__((ext_vector_type(4)));
typedef _Float16 h2f16 __attribute__((ext_vector_type(2)));

// actbuf entry: u32 = (tag16<<16) | fp16bits(act); slot t%NSLOT holds gen t
// (tag = t+1 <= 4097). Validity: min over dwords >= tag<<16.
// Workers elected onto ONE XCD (block 0's). Producers publish with sc1
// (agent) -> local L2; consumers poll with sc1 (agent: L1-BYPASS, L2-served).
// sc0-only polls deadlock: they can hit the never-invalidated per-CU L1.
// d_ws: [0,NSLOT*DIM*4) ring | [+,NWORK*4) progress | [+,NBLK*4) xccmap

__device__ __forceinline__ uint32_t umin32(uint32_t a, uint32_t b) { return a < b ? a : b; }

__device__ __forceinline__ float dot2f(uint32_t packed, h2f16 w, float acc) {
#if __has_builtin(__builtin_amdgcn_fdot2)
  return __builtin_amdgcn_fdot2(__builtin_bit_cast(h2f16, packed), w, acc, false);
#else
  h2f16 a = __builtin_bit_cast(h2f16, packed);
  acc = fmaf((float)a.x, (float)w.x, acc);
  return fmaf((float)a.y, (float)w.y, acc);
#endif
}

template<int NSLOT>
__global__ __launch_bounds__(NTH, 2) void ctrnn_kernel(
    const float* __restrict__ x,        // [TIME, DIM]
    const float* __restrict__ W,        // [DIM, DIM]
    const float* __restrict__ bias,     // [DIM]
    const float* __restrict__ initial,  // [DIM]
    float* __restrict__ out,            // [TIME, DIM]
    uint32_t* __restrict__ actbuf,
    uint32_t* __restrict__ progress,
    uint32_t* __restrict__ xccmap)
{
  const int tid  = threadIdx.x;
  const int lane = tid & 63;
  const int wv   = tid >> 6;            // wave in block (0..7)

  // ---- phase 0: report this block's XCD ----
  if (tid == 0) {
    uint32_t xcc;
    asm volatile("s_getreg_b32 %0, hwreg(HW_REG_XCC_ID)" : "=s"(xcc));
    __hip_atomic_store(&xccmap[blockIdx.x], xcc,
                       __ATOMIC_RELAXED, __HIP_MEMORY_SCOPE_AGENT);
  }
  cooperative_groups::this_grid().sync();

  // ---- phase 1: deterministic election (identical result on all blocks).
  //      Ranks are a permutation of 0..NBLK-1: matching blocks (block-0's
  //      XCD) first in bid order, then the rest. Exactly NWORK workers
  //      always exist; placement only affects speed, never correctness.
  __shared__ uint32_t s_map[NBLK];
  for (int i = tid; i < NBLK; i += NTH)
    s_map[i] = __hip_atomic_load(&xccmap[i], __ATOMIC_RELAXED, __HIP_MEMORY_SCOPE_AGENT);
  __syncthreads();
  const uint32_t target = s_map[0];
  int before = 0, total = 0, beforeN = 0;
  const int bid = blockIdx.x;
  for (int i = 0; i < NBLK; ++i) {
    const bool m = (s_map[i] == target);
    total += m;
    if (i < bid) { before += m; beforeN += !m; }
  }
  const bool mine = (s_map[bid] == target);
  const int rank = mine ? before : (total + beforeN);
  if (rank >= NWORK) return;            // 224 blocks exit; no further grid syncs
  const int wb = rank;

  __shared__ uint32_t lds[2][16 * PITCH];

  const int gwid = wb * WVB + wv;       // worker wave id 0..255
  const int row0 = gwid * RPW;

  // W fragment fp16x2: 8 rows x 32 cols/lane = 128 VGPRs.
  // Lane cols: cb + k*16 + {0..3}, k=0..7; cb = (lane>>2)*128 + (lane&3)*4.
  const int s_c = lane >> 2, rr = lane & 3;
  const int cb  = s_c * 128 + rr * 4;
  h2f16 w2[RPW][16];
  #pragma unroll
  for (int m = 0; m < RPW; ++m) {
    const float* wr = W + (size_t)(row0 + m) * DIM + cb;
    #pragma unroll
    for (int k = 0; k < 8; ++k) {
      w2[m][2*k]   = h2f16{(_Float16)wr[k*16 + 0], (_Float16)wr[k*16 + 1]};
      w2[m][2*k+1] = h2f16{(_Float16)wr[k*16 + 2], (_Float16)wr[k*16 + 3]};
    }
  }

  // State: lanes 0..7 own rows row0..row0+7. x pipeline 2 deep.
  float v = 0.f, bj = 0.f, xv = 0.f, xw = 0.f;
  if (lane < RPW) {
    const int j = row0 + lane;
    v  = initial[j];
    bj = bias[j];
    xv = x[j];
    xw = x[DIM + j];
    out[j] = v;
    const float a0 = 1.0f / (1.0f + __expf(-(v + bj)));
    __half h = __float2half_rn(a0);
    uint16_t hb; __builtin_memcpy(&hb, &h, 2);
    __hip_atomic_store(&actbuf[j], (1u << 16) | hb,
                       __ATOMIC_RELAXED, __HIP_MEMORY_SCOPE_AGENT);
  }

  // Poll/stage geometry: wave wv owns entries [wv*256, wv*256+256);
  // this lane's quad at entry e0; LDS slice e0>>7, word e0&127.
  const int e0   = wv * 256 + lane * 4;
  const int dstw = (e0 >> 7) * PITCH + (e0 & 127);

  uint32_t prog_seen = 0;

  for (int t = 0; t < TIME_STEPS - 1; ++t) {
    const int b = t & 1;
    const uint32_t needtag = (uint32_t)(t + 1);
    const uint32_t thresh  = needtag << 16;

    // ---- poll own quad: sc1 = agent scope (L1-bypass, local-L2-served) ----
    const uint32_t* qsrc = actbuf + (size_t)(t & (NSLOT - 1)) * DIM + e0;
    u32x4 q;
    for (;;) {
      asm volatile("global_load_dwordx4 %0, %1, off sc1\n\t"
                   "s_waitcnt vmcnt(0)"
                   : "=v"(q) : "v"(qsrc) : "memory");
      const uint32_t mn = umin32(umin32(q[0], q[1]), umin32(q[2], q[3]));
      if (mn >= thresh) break;
    }
    *reinterpret_cast<u32x4*>(&lds[b][dstw]) = q;

    __syncthreads();  // slot t fully staged in lds[b]

    if (tid == 0)
      __hip_atomic_store(&progress[wb], needtag,
                         __ATOMIC_RELAXED, __HIP_MEMORY_SCOPE_AGENT);

    // x[t+2] prefetch (~1 step of slack; next poll's vmcnt absorbs it).
    float xn = 0.f;
    if (lane < RPW && t + 2 < TIME_STEPS) xn = x[(size_t)(t + 2) * DIM + row0 + lane];

    // ---- dot: 8 rows x 32 cols per lane from LDS (2-way banks = free) ----
    float a0 = 0.f, a1 = 0.f, a2 = 0.f, a3 = 0.f;
    float a4 = 0.f, a5 = 0.f, a6 = 0.f, a7 = 0.f;
    #pragma unroll
    for (int k = 0; k < 8; ++k) {
      const u32x4 qq = *reinterpret_cast<const u32x4*>(
          &lds[b][s_c * PITCH + rr * 4 + k * 16]);
      const uint32_t lo = __builtin_amdgcn_perm(qq[1], qq[0], 0x05040100u);
      const uint32_t hi = __builtin_amdgcn_perm(qq[3], qq[2], 0x05040100u);
      a0 = dot2f(lo, w2[0][2*k], a0); a0 = dot2f(hi, w2[0][2*k+1], a0);
      a1 = dot2f(lo, w2[1][2*k], a1); a1 = dot2f(hi, w2[1][2*k+1], a1);
      a2 = dot2f(lo, w2[2][2*k], a2); a2 = dot2f(hi, w2[2][2*k+1], a2);
      a3 = dot2f(lo, w2[3][2*k], a3); a3 = dot2f(hi, w2[3][2*k+1], a3);
      a4 = dot2f(lo, w2[4][2*k], a4); a4 = dot2f(hi, w2[4][2*k+1], a4);
      a5 = dot2f(lo, w2[5][2*k], a5); a5 = dot2f(hi, w2[5][2*k+1], a5);
      a6 = dot2f(lo, w2[6][2*k], a6); a6 = dot2f(hi, w2[6][2*k+1], a6);
      a7 = dot2f(lo, w2[7][2*k], a7); a7 = dot2f(hi, w2[7][2*k+1], a7);
    }

    // ---- merge-reduce: lane l ends with row (l&7) total ----
    const float t0 = a0 + __shfl_xor(a0, 1, 64);
    const float t1 = a1 + __shfl_xor(a1, 1, 64);
    const float t2 = a2 + __shfl_xor(a2, 1, 64);
    const float t3 = a3 + __shfl_xor(a3, 1, 64);
    const float t4 = a4 + __shfl_xor(a4, 1, 64);
    const float t5 = a5 + __shfl_xor(a5, 1, 64);
    const float t6 = a6 + __shfl_xor(a6, 1, 64);
    const float t7 = a7 + __shfl_xor(a7, 1, 64);
    float b0 = (lane & 1) ? t1 : t0;
    float b1 = (lane & 1) ? t3 : t2;
    float b2 = (lane & 1) ? t5 : t4;
    float b3 = (lane & 1) ? t7 : t6;
    b0 += __shfl_xor(b0, 2, 64);
    b1 += __shfl_xor(b1, 2, 64);
    b2 += __shfl_xor(b2, 2, 64);
    b3 += __shfl_xor(b3, 2, 64);
    float c0 = (lane & 2) ? b1 : b0;
    float c1 = (lane & 2) ? b3 : b2;
    c0 += __shfl_xor(c0, 4, 64);
    c1 += __shfl_xor(c1, 4, 64);
    float p = (lane & 4) ? c1 : c0;
    p += __shfl_xor(p, 8, 64);
    p += __shfl_xor(p, 16, 64);
    p += __shfl_xor(p, 32, 64);

    // ---- WAR gate: publish gen t+1 over slot (t+1)%NSLOT only after all
    //      worker blocks staged gen t+2-NSLOT. Fires ~every NSLOT-1 steps. ----
    if (t >= NSLOT - 1) {
      const uint32_t need = (uint32_t)(t + 2 - NSLOT);
      if (need > prog_seen) {
        for (;;) {
          uint32_t mn = __hip_atomic_load(&progress[lane & (NWORK - 1)],
                            __ATOMIC_RELAXED, __HIP_MEMORY_SCOPE_AGENT);
          uint32_t qv;
          qv = (uint32_t)__shfl_xor((int)mn, 1, 64);  mn = umin32(mn, qv);
          qv = (uint32_t)__shfl_xor((int)mn, 2, 64);  mn = umin32(mn, qv);
          qv = (uint32_t)__shfl_xor((int)mn, 4, 64);  mn = umin32(mn, qv);
          qv = (uint32_t)__shfl_xor((int)mn, 8, 64);  mn = umin32(mn, qv);
          qv = (uint32_t)__shfl_xor((int)mn, 16, 64); mn = umin32(mn, qv);
          if (mn >= need) { prog_seen = mn; break; }
        }
      }
    }

    // ---- state update + out + publish (lanes 0..7: 32B/wave, sc1) ----
    if (lane < RPW) {
      v  = 0.9f * v + 0.1f * (p + xv);
      xv = xw;
      xw = xn;
      out[(size_t)(t + 1) * DIM + row0 + lane] = v;
      const float a = 1.0f / (1.0f + __expf(-(v + bj)));
      __half h = __float2half_rn(a);
      uint16_t hb; __builtin_memcpy(&hb, &h, 2);
      const uint32_t e = ((uint32_t)(t + 2) << 16) | hb;
      __hip_atomic_store(&actbuf[(size_t)((t + 1) & (NSLOT - 1)) * DIM + row0 + lane], e,
                         __ATOMIC_RELAXED, __HIP_MEMORY_SCOPE_AGENT);
    }
  }
}

extern "C" void kernel_launch(void* const* d_in, const int* in_sizes, int n_in,
                              void* d_out, int out_size, void* d_ws, size_t ws_size,
                              hipStream_t stream) {
  const float* x       = (const float*)d_in[0];
  const float* W       = (const float*)d_in[1];
  const float* bias    = (const float*)d_in[2];
  const float* initial = (const float*)d_in[3];
  float* out           = (float*)d_out;

  uint32_t* actbuf = (uint32_t*)d_ws;

  const size_t need8 = ((size_t)8 * DIM + NWORK + NBLK) * 4;
  void* kfun;
  size_t ringwords;
  if (ws_size >= need8) { kfun = (void*)ctrnn_kernel<8>; ringwords = (size_t)8 * DIM; }
  else                  { kfun = (void*)ctrnn_kernel<2>; ringwords = (size_t)2 * DIM; }

  uint32_t* progress = actbuf + ringwords;
  uint32_t* xccmap   = progress + NWORK;

  // Tags/progress are generation counters — clear every call (capture-safe).
  hipMemsetAsync(d_ws, 0, (ringwords + NWORK + NBLK) * 4, stream);

  void* args[] = { (void*)&x, (void*)&W, (void*)&bias, (void*)&initial,
                   (void*)&out, (void*)&actbuf, (void*)&progress, (void*)&xccmap };
  hipLaunchCooperativeKernel(kfun, dim3(NBLK), dim3(NTH), args, 0, stream);
}